// Round 1
// 223.087 us; speedup vs baseline: 1.0363x; 1.0363x over previous
//
#include <hip/hip_runtime.h>
#include <math.h>

#define BTOT 131072
#define NBK 3
#define SS 16
#define NA 9
#define BAD 25      // SS+NA
#define STR 28      // padded row stride in the fp32 weight image
#define VD 128
#define CM 10
#define OUTD 51     // NBK*SS + 3
#define EPS 1e-8f

// ---- fp32 folded-weight image (float offsets in ws) ----
#define O_GQK  0        // 25 x 28  full Wq^T Wk
#define O_GQQ  700      // 25 x 28  lower-tri (off-diag x2) of Wq^T Wq
#define O_GKK  1400     // 25 x 28  lower-tri (off-diag x2) of Wk^T Wk
#define O_V1   2100     // 28: Wq^T bk
#define O_V2   2128     // 28: Wk^T bq
#define O_VQ   2156     // 28: Wq^T bq
#define O_VK   2184     // 28: Wk^T bk
#define O_C    2212     // c0, cq, ck, pad
#define O_M    2216     // (dead region, never read by main; not filled)
#define O_MB   5800     // (dead)
#define O_W2T  5928     // (dead)
#define O_B2   7976     // 16
#define O_WC1  7992     // 10 x 84
#define O_BC1  8832     // 12
#define O_WC2  8844     // 3 x 12
#define O_BC2  8880     // 4
#define LDS_F  8884
// ---- bf16 MFMA-packed B-fragments appended after the fp32 image ----
#define O_PKM  LDS_F          // 4096 ushorts = 2048 floats
#define O_PKW2 (LDS_F + 2048) // 2048 ushorts = 1024 floats
#define PKM_N  4096
#define PKW2_N 2048

#define NDOT  (O_M + PKM_N)   // 2216 fp32 dots + 4096 pkM dots = 6312
#define NCOPY (16 + 840 + 12 + 36 + 4 + PKW2_N)  // 2956

typedef __attribute__((ext_vector_type(8))) short short8;
typedef __attribute__((ext_vector_type(4))) float floatx4;

__device__ __forceinline__ float fast_sigmoid(float x) {
    return __builtin_amdgcn_rcpf(1.0f + __expf(-x));
}

__device__ __forceinline__ unsigned short f2bf(float f) {
    unsigned int u = __float_as_uint(f);
    u += 0x7FFFu + ((u >> 16) & 1u);   // round-to-nearest-even
    return (unsigned short)(u >> 16);
}

// ---------------- prep: wave-per-output 128-length dot products ----------------
// Old prep ran 59 blocks with one serial 128-iter loop per thread -> pure
// latency exposure (~100 us). Now: one wave per output, lane-parallel dot +
// shfl_xor butterfly reduce. Dead ws regions (O_M..O_W2T) are skipped.
__global__ __launch_bounds__(256) void prep_dots(
    const float* __restrict__ Wq, const float* __restrict__ bq,
    const float* __restrict__ Wk, const float* __restrict__ bk,
    const float* __restrict__ Wv, const float* __restrict__ bv,
    const float* __restrict__ W1, const float* __restrict__ b1,
    float* __restrict__ ws) {
    int lane = threadIdx.x & 63;
    int gidx = blockIdx.x * 4 + (threadIdx.x >> 6);
    if (gidx >= NDOT) return;

    const float* pa = bq;  const float* pb = bk;   // safe defaults
    int sa = 1, sb = 1;
    float scale = 1.0f, bias = 0.0f;
    bool zero = false;
    bool isbf = false; int bfpos = 0;

    if (gidx < O_M) {
        int idx = gidx;
        if (idx < O_GQQ) {
            int e = idx / STR, f = idx % STR;
            if (f < BAD) { pa = Wq + e; sa = BAD; pb = Wk + f; sb = BAD; }
            else zero = true;
        } else if (idx < O_GKK) {
            int j = idx - O_GQQ; int e = j / STR, f = j % STR;
            if (f < BAD && f <= e) { pa = Wq + e; sa = BAD; pb = Wq + f; sb = BAD; scale = (f == e) ? 1.0f : 2.0f; }
            else zero = true;
        } else if (idx < O_V1) {
            int j = idx - O_GKK; int e = j / STR, f = j % STR;
            if (f < BAD && f <= e) { pa = Wk + e; sa = BAD; pb = Wk + f; sb = BAD; scale = (f == e) ? 1.0f : 2.0f; }
            else zero = true;
        } else if (idx < O_V2) {
            int e = idx - O_V1;
            if (e < BAD) { pa = Wq + e; sa = BAD; pb = bk; }
            else zero = true;
        } else if (idx < O_VQ) {
            int e = idx - O_V2;
            if (e < BAD) { pa = Wk + e; sa = BAD; pb = bq; }
            else zero = true;
        } else if (idx < O_VK) {
            int e = idx - O_VQ;
            if (e < BAD) { pa = Wq + e; sa = BAD; pb = bq; }
            else zero = true;
        } else if (idx < O_C) {
            int e = idx - O_VK;
            if (e < BAD) { pa = Wk + e; sa = BAD; pb = bk; }
            else zero = true;
        } else {
            int j = idx - O_C;
            if (j == 0)      { pa = bq; pb = bk; }
            else if (j == 1) { pa = bq; pb = bq; }
            else if (j == 2) { pa = bk; pb = bk; }
            else zero = true;
        }
    } else {
        // pkM B-frag: B[k][n], n = tile*16 + (l&15), k = (l>>4)*8 + j
        int p = gidx - O_M;
        isbf = true; bfpos = p;
        int l2 = (p >> 3) & 63, j = p & 7;
        int n = (p >> 9) * 16 + (l2 & 15);
        int k = ((l2 >> 4) << 3) + j;
        if (k < BAD)       { pa = W1 + n * VD; pb = Wv + k; sb = BAD; scale = 2.0f; }
        else if (k == BAD) { pa = W1 + n * VD; pb = bv; scale = 2.0f; bias = 2.0f * b1[n]; }
        else zero = true;
    }

    float s = 0.0f;
    if (!zero)
        s = pa[sa * lane] * pb[sb * lane] + pa[sa * (lane + 64)] * pb[sb * (lane + 64)];
    #pragma unroll
    for (int off = 1; off < 64; off <<= 1) s += __shfl_xor(s, off);
    float val = zero ? 0.0f : (s * scale + bias);
    if (lane == 0) {
        if (isbf) ((unsigned short*)(ws + O_PKM))[bfpos] = f2bf(val);
        else ws[gidx] = val;
    }
}

__global__ __launch_bounds__(256) void prep_copy(
    const float* __restrict__ W2, const float* __restrict__ b2,
    const float* __restrict__ Wc1, const float* __restrict__ bc1,
    const float* __restrict__ Wc2, const float* __restrict__ bc2,
    float* __restrict__ ws) {
    int c = blockIdx.x * 256 + threadIdx.x;
    if (c >= NCOPY) return;
    if (c < 16) { ws[O_B2 + c] = b2[c]; return; }
    c -= 16;
    if (c < 840) {
        int m = c / 84, r = c % 84, i = r / STR, f = r % STR;
        ws[O_WC1 + c] = (f < BAD) ? Wc1[m * (NBK * BAD) + i * BAD + f] : 0.0f;
        return;
    }
    c -= 840;
    if (c < 12) { ws[O_BC1 + c] = (c < CM) ? bc1[c] : 0.0f; return; }
    c -= 12;
    if (c < 36) { int o = c / 12, mm = c % 12; ws[O_WC2 + c] = (mm < CM) ? Wc2[o * CM + mm] : 0.0f; return; }
    c -= 36;
    if (c < 4) { ws[O_BC2 + c] = (c < 3) ? bc2[c] : 0.0f; return; }
    c -= 4;
    // pkW2 B-frag: B[k][o], o = l&15, k = kt*32 + (l>>4)*8 + j
    int kt = c >> 9, l = (c >> 3) & 63, j = c & 7;
    int o = l & 15;
    int k = kt * 32 + ((l >> 4) << 3) + j;
    ((unsigned short*)(ws + O_PKW2))[c] = f2bf(W2[o * VD + k]);
}

// ---------------- fused main kernel ----------------
// Phase 1 (thread = element): attention scores + conf MLP; a_tilde -> LDS bf16.
// At is WAVE-PRIVATE (wave w writes rows [192w,192w+192) and reads only those),
// so __syncthreads is replaced by a wave-local lgkmcnt fence.
// Phase 2 (per wave): GEMM1 with swapped operands: mfma(pkM, af) = P^T tile, so
// lane (m,q) reg (nt,r) holds P[tt*16+m][nt*16+q*4+r] -- P row is lane-local.
// tanh -> v_cvt_pk_bf16 pairs -> ds_bpermute among the 4 lanes sharing m builds
// the GEMM2 A-frag directly in registers: no P LDS buffer, no barrier.
__global__ __launch_bounds__(256) void main_kernel(
    const float* __restrict__ states, const float* __restrict__ action,
    const int* __restrict__ block_id,
    const float* __restrict__ ws, float* __restrict__ out) {
    __shared__ __align__(16) unsigned short At[768 * 40];   // 61440 B

    int t = threadIdx.x;
    int elem = blockIdx.x * 256 + t;

    const float* st = states + (long)elem * (NBK * SS);
    const float* ac = action + (long)elem * NA;
    const int* bid = block_id + (long)elem * NBK;

    // ---- build ba[3][25] (all indices compile-time) ----
    float ba[NBK * BAD];
    #pragma unroll
    for (int i = 0; i < NBK; ++i) {
        const float4* s4 = (const float4*)(st + i * SS);
        #pragma unroll
        for (int w = 0; w < 4; ++w) {
            float4 v = s4[w];
            ba[i * BAD + w * 4 + 0] = v.x;
            ba[i * BAD + w * 4 + 1] = v.y;
            ba[i * BAD + w * 4 + 2] = v.z;
            ba[i * BAD + w * 4 + 3] = v.w;
        }
        bool sel = (bid[i] == 1);
        #pragma unroll
        for (int c = 0; c < NA; ++c)
            ba[i * BAD + SS + c] = sel ? ac[c] : -1.0f;
    }

    // ---- confidence MLP ----
    {
        float hm[CM];
        #pragma unroll
        for (int m = 0; m < CM; ++m) {
            float s = ws[O_BC1 + m];
            #pragma unroll
            for (int i = 0; i < NBK; ++i)
                #pragma unroll
                for (int f = 0; f < BAD; ++f)
                    s += ws[O_WC1 + m * 84 + i * STR + f] * ba[i * BAD + f];
            hm[m] = fast_sigmoid(s);
        }
        float* op = out + (long)elem * OUTD;
        #pragma unroll
        for (int o = 0; o < 3; ++o) {
            float s = ws[O_BC2 + o];
            #pragma unroll
            for (int m = 0; m < CM; ++m) s += ws[O_WC2 + o * 12 + m] * hm[m];
            op[48 + o] = fast_sigmoid(s);
        }
    }

    // ---- linear score terms ----
    float s1[NBK], s2[NBK], dq[NBK], dk[NBK];
    #pragma unroll
    for (int p = 0; p < NBK; ++p) {
        float a1 = 0.f, a2 = 0.f, aq = 0.f, ak = 0.f;
        #pragma unroll
        for (int e = 0; e < BAD; ++e) {
            float b = ba[p * BAD + e];
            a1 += ws[O_V1 + e] * b;
            a2 += ws[O_V2 + e] * b;
            aq += ws[O_VQ + e] * b;
            ak += ws[O_VK + e] * b;
        }
        s1[p] = a1; s2[p] = a2; dq[p] = aq; dk[p] = ak;
    }
    float c0 = ws[O_C + 0], cq = ws[O_C + 1], ck = ws[O_C + 2];

    // ---- bilinear numerators ----
    float num[NBK][NBK] = {{0.f,0.f,0.f},{0.f,0.f,0.f},{0.f,0.f,0.f}};
    #pragma unroll
    for (int e = 0; e < BAD; ++e) {
        float t0 = 0.f, t1 = 0.f, t2 = 0.f;
        #pragma unroll
        for (int f = 0; f < BAD; ++f) {
            float g = ws[O_GQK + e * STR + f];
            t0 += g * ba[0 * BAD + f];
            t1 += g * ba[1 * BAD + f];
            t2 += g * ba[2 * BAD + f];
        }
        #pragma unroll
        for (int i = 0; i < NBK; ++i) {
            float be = ba[i * BAD + e];
            num[i][0] += be * t0;
            num[i][1] += be * t1;
            num[i][2] += be * t2;
        }
    }

    // ---- quadratic forms via scaled lower triangles ----
    float qn2[NBK] = {0.f, 0.f, 0.f}, kn2[NBK] = {0.f, 0.f, 0.f};
    #pragma unroll
    for (int e = 0; e < BAD; ++e) {
        float pq0 = 0.f, pq1 = 0.f, pq2 = 0.f;
        float pk0 = 0.f, pk1 = 0.f, pk2 = 0.f;
        #pragma unroll
        for (int f = 0; f <= e; ++f) {
            float gq = ws[O_GQQ + e * STR + f];
            float gk = ws[O_GKK + e * STR + f];
            float b0 = ba[0 * BAD + f], b1v = ba[1 * BAD + f], b2v = ba[2 * BAD + f];
            pq0 += gq * b0; pq1 += gq * b1v; pq2 += gq * b2v;
            pk0 += gk * b0; pk1 += gk * b1v; pk2 += gk * b2v;
        }
        qn2[0] += ba[0 * BAD + e] * pq0;
        qn2[1] += ba[1 * BAD + e] * pq1;
        qn2[2] += ba[2 * BAD + e] * pq2;
        kn2[0] += ba[0 * BAD + e] * pk0;
        kn2[1] += ba[1 * BAD + e] * pk1;
        kn2[2] += ba[2 * BAD + e] * pk2;
    }
    #pragma unroll
    for (int p = 0; p < NBK; ++p) {
        qn2[p] += 2.0f * dq[p] + cq;
        kn2[p] += 2.0f * dk[p] + ck;
    }

    // ---- softmax over j ----
    float att[NBK][NBK];
    {
        float kn[NBK];
        #pragma unroll
        for (int j = 0; j < NBK; ++j) kn[j] = __builtin_amdgcn_sqrtf(fmaxf(kn2[j], 0.0f));
        #pragma unroll
        for (int i = 0; i < NBK; ++i) {
            float qn = __builtin_amdgcn_sqrtf(fmaxf(qn2[i], 0.0f));
            float dv[NBK];
            #pragma unroll
            for (int j = 0; j < NBK; ++j)
                dv[j] = (num[i][j] + s1[i] + s2[j] + c0) *
                        __builtin_amdgcn_rcpf(fmaxf(qn * kn[j], EPS));
            float mx = fmaxf(dv[0], fmaxf(dv[1], dv[2]));
            float e0 = __expf(dv[0] - mx);
            float e1 = __expf(dv[1] - mx);
            float e2 = __expf(dv[2] - mx);
            float inv = __builtin_amdgcn_rcpf(e0 + e1 + e2);
            att[i][0] = e0 * inv;
            att[i][1] = e1 * inv;
            att[i][2] = e2 * inv;
        }
    }

    // ---- a_tilde (in place) ----
    #pragma unroll
    for (int e = 0; e < BAD; ++e) {
        float b0 = ba[0 * BAD + e], b1v = ba[1 * BAD + e], b2v = ba[2 * BAD + e];
        ba[0 * BAD + e] = att[0][0] * b0 + att[0][1] * b1v + att[0][2] * b2v;
        ba[1 * BAD + e] = att[1][0] * b0 + att[1][1] * b1v + att[1][2] * b2v;
        ba[2 * BAD + e] = att[2][0] * b0 + att[2][1] * b1v + att[2][2] * b2v;
    }

    // ---- write a_tilde rows to LDS as bf16 (col 25 = 1.0 bias, 26-31 = 0) ----
    #pragma unroll
    for (int i = 0; i < NBK; ++i) {
        unsigned int* dst = (unsigned int*)&At[(t * 3 + i) * 40];
        #pragma unroll
        for (int pr = 0; pr < 12; ++pr)
            dst[pr] = (unsigned int)f2bf(ba[i * BAD + 2 * pr]) |
                      ((unsigned int)f2bf(ba[i * BAD + 2 * pr + 1]) << 16);
        dst[12] = (unsigned int)f2bf(ba[i * BAD + 24]) | (0x3F80u << 16);
        dst[13] = 0u; dst[14] = 0u; dst[15] = 0u;
    }

    // At is wave-private: wave-local fence instead of __syncthreads.
    asm volatile("s_waitcnt lgkmcnt(0)" ::: "memory");

    // ================= phase 2: MFMA (no block barrier, no P LDS) =================
    int lane = t & 63, w = t >> 6;
    int m = lane & 15, q = lane >> 4;
    const short8* pkM = (const short8*)(ws + O_PKM);
    const short8* pkW2 = (const short8*)(ws + O_PKW2);
    float b2v = ws[O_B2 + m];   // exact fp32 bias, col o = m
    long blockbase = (long)blockIdx.x * 256;
    // bpermute source lanes: same m, q' = 2*(q&1) (+1): byte addr = lane*4
    int addrA = ((q & 1) ? (m + 32) : m) << 2;
    int addrB = addrA + 64;
    bool hiSel = (q >= 2);   // selects nt_s = 2kt + (q>>1)

    for (int tt = 0; tt < 12; ++tt) {
        int tile = w * 12 + tt;            // rows tile*16 .. +15
        // B'-frag = At[tile*16+(lane&15)][q*8 .. +8] (same bytes as old A-frag)
        short8 af = *(const short8*)&At[(tile * 16 + m) * 40 + q * 8];
        // GEMM1 swapped: D = M^T_tile * At_tile^T = P^T tile.
        // lane (m,q) reg (nt,r) = P[tile*16+m][nt*16 + q*4 + r]
        floatx4 accT[8];
        #pragma unroll
        for (int nt = 0; nt < 8; ++nt) {
            floatx4 z = {0.f, 0.f, 0.f, 0.f};
            accT[nt] = __builtin_amdgcn_mfma_f32_16x16x32_bf16(pkM[nt * 64 + lane], af, z, 0, 0, 0);
        }
        // tanh + pack adjacent-col pairs into bf16 dwords
        unsigned int pk[8][2];
        #pragma unroll
        for (int nt = 0; nt < 8; ++nt) {
            float x0 = fmaf(-2.0f, __builtin_amdgcn_rcpf(1.0f + __expf(accT[nt][0])), 1.0f);
            float x1 = fmaf(-2.0f, __builtin_amdgcn_rcpf(1.0f + __expf(accT[nt][1])), 1.0f);
            float x2 = fmaf(-2.0f, __builtin_amdgcn_rcpf(1.0f + __expf(accT[nt][2])), 1.0f);
            float x3 = fmaf(-2.0f, __builtin_amdgcn_rcpf(1.0f + __expf(accT[nt][3])), 1.0f);
            asm("v_cvt_pk_bf16_f32 %0, %1, %2" : "=v"(pk[nt][0]) : "v"(x0), "v"(x1));
            asm("v_cvt_pk_bf16_f32 %0, %1, %2" : "=v"(pk[nt][1]) : "v"(x2), "v"(x3));
        }
        // GEMM2: A2[m][kt*32+q*8+j] gathered via register bpermute.
        // target (m,q,kt,u): src lane m+16*((2q+(u>>1))&3), src reg pk[2kt+(q>>1)][u&1]
        floatx4 acc2 = {0.f, 0.f, 0.f, 0.f};
        #pragma unroll
        for (int kt = 0; kt < 4; ++kt) {
            int lo0 = __builtin_amdgcn_ds_bpermute(addrA, (int)pk[2 * kt][0]);
            int hi0 = __builtin_amdgcn_ds_bpermute(addrA, (int)pk[2 * kt + 1][0]);
            int lo1 = __builtin_amdgcn_ds_bpermute(addrA, (int)pk[2 * kt][1]);
            int hi1 = __builtin_amdgcn_ds_bpermute(addrA, (int)pk[2 * kt + 1][1]);
            int lo2 = __builtin_amdgcn_ds_bpermute(addrB, (int)pk[2 * kt][0]);
            int hi2 = __builtin_amdgcn_ds_bpermute(addrB, (int)pk[2 * kt + 1][0]);
            int lo3 = __builtin_amdgcn_ds_bpermute(addrB, (int)pk[2 * kt][1]);
            int hi3 = __builtin_amdgcn_ds_bpermute(addrB, (int)pk[2 * kt + 1][1]);
            union { unsigned int u[4]; short8 s; } a2u;
            a2u.u[0] = (unsigned int)(hiSel ? hi0 : lo0);
            a2u.u[1] = (unsigned int)(hiSel ? hi1 : lo1);
            a2u.u[2] = (unsigned int)(hiSel ? hi2 : lo2);
            a2u.u[3] = (unsigned int)(hiSel ? hi3 : lo3);
            acc2 = __builtin_amdgcn_mfma_f32_16x16x32_bf16(a2u.s, pkW2[kt * 64 + lane], acc2, 0, 0, 0);
        }
        // epilogue: + states + b2, store (D2: row=q*4+r, col o=m)
        #pragma unroll
        for (int r = 0; r < 4; ++r) {
            int lrow = tile * 16 + q * 4 + r;          // 0..767
            int et = lrow / 3, i = lrow - et * 3;      // const-div magic
            long ge = blockbase + et;
            float base = states[ge * 48 + i * 16 + m];
            out[ge * OUTD + i * 16 + m] = acc2[r] + base + b2v;
        }
    }
}

extern "C" void kernel_launch(void* const* d_in, const int* in_sizes, int n_in,
                              void* d_out, int out_size, void* d_ws, size_t ws_size,
                              hipStream_t stream) {
    const float* states = (const float*)d_in[0];
    const float* action = (const float*)d_in[1];
    const int* block_id = (const int*)d_in[2];
    const float* Wq = (const float*)d_in[3];
    const float* bq = (const float*)d_in[4];
    const float* Wk = (const float*)d_in[5];
    const float* bk = (const float*)d_in[6];
    const float* Wv = (const float*)d_in[7];
    const float* bv = (const float*)d_in[8];
    const float* W1 = (const float*)d_in[9];
    const float* b1 = (const float*)d_in[10];
    const float* W2 = (const float*)d_in[11];
    const float* b2 = (const float*)d_in[12];
    const float* Wc1 = (const float*)d_in[13];
    const float* bc1 = (const float*)d_in[14];
    const float* Wc2 = (const float*)d_in[15];
    const float* bc2 = (const float*)d_in[16];
    float* out = (float*)d_out;
    float* ws = (float*)d_ws;

    hipLaunchKernelGGL(prep_dots, dim3((NDOT + 3) / 4), dim3(256), 0, stream,
                       Wq, bq, Wk, bk, Wv, bv, W1, b1, ws);
    hipLaunchKernelGGL(prep_copy, dim3((NCOPY + 255) / 256), dim3(256), 0, stream,
                       W2, b2, Wc1, bc1, Wc2, bc2, ws);
    hipLaunchKernelGGL(main_kernel, dim3(BTOT / 256), dim3(256), 0, stream,
                       states, action, block_id, ws, out);
}